// Round 2
// baseline (7370.737 us; speedup 1.0000x reference)
//
#include <hip/hip_runtime.h>
#include <stdint.h>

#define NODES   8192
#define FIN     16
#define HC1     64
#define HC2     1024
#define DTOT    1048576
#define NEG     0.2f
#define NBLK    1024
#define MAGIC   0x5A17C0DE

typedef unsigned short u16;

__device__ __forceinline__ float b2f(u16 s){ return __uint_as_float(((unsigned)s)<<16); }
__device__ __forceinline__ u16 f2b(float f){
    unsigned u = __float_as_uint(f);
    unsigned r = u + 0x7fffu + ((u>>16)&1u);
    return (u16)(r>>16);
}
__device__ __forceinline__ float lrelu(float x){ return x > 0.f ? x : NEG*x; }
__device__ __forceinline__ float ldf(const void* p, long i, int isf){
    return isf ? ((const float*)p)[i] : b2f(((const u16*)p)[i]);
}
__device__ __forceinline__ int esrc(const int* e, int i, int i64){ return i64 ? e[2*i] : e[i]; }
__device__ __forceinline__ int edst(const int* e, int i, int E, int i64){ return i64 ? e[2*(E+i)] : e[E+i]; }

// ---- device-scope generation barrier; bar[0]=count, bar[1]=gen ----
__device__ __forceinline__ void gbar(int* bar){
    __syncthreads();
    if(threadIdx.x==0){
        __threadfence();
        int g = __hip_atomic_load(&bar[1], __ATOMIC_RELAXED, __HIP_MEMORY_SCOPE_AGENT);
        int a = __hip_atomic_fetch_add(&bar[0], 1, __ATOMIC_ACQ_REL, __HIP_MEMORY_SCOPE_AGENT);
        if(a == NBLK-1){
            __hip_atomic_store(&bar[0], 0, __ATOMIC_RELAXED, __HIP_MEMORY_SCOPE_AGENT);
            __hip_atomic_fetch_add(&bar[1], 1, __ATOMIC_RELEASE, __HIP_MEMORY_SCOPE_AGENT);
        } else {
            while(__hip_atomic_load(&bar[1], __ATOMIC_ACQUIRE, __HIP_MEMORY_SCOPE_AGENT) == g)
                __builtin_amdgcn_s_sleep(2);
        }
        __threadfence();
    }
    __syncthreads();
}

// ---- fused head GEMV partial (per wave), no x2 unroll to keep VGPR<=128 ----
template<int COLS, int NW>
__device__ __forceinline__ void gemv_part(const void* __restrict__ W, const u16* __restrict__ hbf,
        float* __restrict__ scratch, int wid, int lane, int isf){
    const int GR    = COLS/8;
    const int KSTEP = 64/GR;
    const int ITERS = DTOT/(NW*KSTEP);
    int cg  = (lane % GR)*8;
    int kof = lane / GR;
    float acc[8][8];
    #pragma unroll
    for(int b=0;b<8;b++)
        #pragma unroll
        for(int c=0;c<8;c++) acc[b][c]=0.f;
    for(int it=0; it<ITERS; ++it){
        int k0 = (it*NW + wid)*KSTEP + kof;
        float wv0[8];
        if(isf){
            float4 a0 = *(const float4*)((const float*)W + (size_t)k0*COLS + cg);
            float4 b0 = *(const float4*)((const float*)W + (size_t)k0*COLS + cg + 4);
            wv0[0]=a0.x;wv0[1]=a0.y;wv0[2]=a0.z;wv0[3]=a0.w;wv0[4]=b0.x;wv0[5]=b0.y;wv0[6]=b0.z;wv0[7]=b0.w;
        } else {
            ushort4 a0 = *(const ushort4*)((const u16*)W + (size_t)k0*COLS + cg);
            ushort4 b0 = *(const ushort4*)((const u16*)W + (size_t)k0*COLS + cg + 4);
            wv0[0]=b2f(a0.x);wv0[1]=b2f(a0.y);wv0[2]=b2f(a0.z);wv0[3]=b2f(a0.w);
            wv0[4]=b2f(b0.x);wv0[5]=b2f(b0.y);wv0[6]=b2f(b0.z);wv0[7]=b2f(b0.w);
        }
        float hv0[8];
        #pragma unroll
        for(int b=0;b<8;b++) hv0[b] = b2f(hbf[(size_t)b*DTOT + k0]);
        #pragma unroll
        for(int b=0;b<8;b++)
            #pragma unroll
            for(int c=0;c<8;c++) acc[b][c] += hv0[b]*wv0[c];
    }
    #pragma unroll
    for(int m=GR;m<64;m<<=1){
        #pragma unroll
        for(int b=0;b<8;b++)
            #pragma unroll
            for(int c=0;c<8;c++) acc[b][c] += __shfl_xor(acc[b][c], m);
    }
    int q = lane / GR;
    if(q < 8){
        float4 o0, o1;
        o0.x=acc[q][0]; o0.y=acc[q][1]; o0.z=acc[q][2]; o0.w=acc[q][3];
        o1.x=acc[q][4]; o1.y=acc[q][5]; o1.z=acc[q][6]; o1.w=acc[q][7];
        float* dst = scratch + (size_t)wid*COLS*8 + q*COLS + cg;
        *(float4*)dst       = o0;
        *(float4*)(dst + 4) = o1;
    }
}

// =================== the whole pipeline in one dispatch ===================
__global__ __launch_bounds__(256,4) void k_mega(
        const void* __restrict__ x, const int* __restrict__ ed, int E,
        const void* __restrict__ W1, const void* __restrict__ as1w, const void* __restrict__ ad1w,
        const void* __restrict__ b1,
        const void* __restrict__ W2, const void* __restrict__ as2w, const void* __restrict__ ad2w,
        const void* __restrict__ b2,
        const void* __restrict__ advw, const void* __restrict__ advb,
        const void* __restrict__ v1w, const void* __restrict__ v1b,
        const void* __restrict__ v2w, const void* __restrict__ b2v,
        const void* __restrict__ v3w, const void* __restrict__ b3v,
        int* counts, int* offs, int* cursor, int* csr,
        float* g1, float* as1, float* ad1,
        u16* g2, float* as2, float* ad2, u16* hbf,
        float* s1, float* s2, float* v1a, float* adva,
        int* bar, void* out){
    int t = threadIdx.x, bid = blockIdx.x;
    int lane = t & 63, wv = t >> 6;
    __shared__ int det[2];
    __shared__ __align__(16) char smem[10496];

    // ---- per-block dtype / index-width detection (no cross-block dep) ----
    if(t<2) det[t]=0;
    __syncthreads();
    {
        int bad=0, z=0;
        const u16* xs = (const u16*)x;
        for(int i=t;i<1024;i+=256){
            u16 u = xs[i];
            float a = fabsf(b2f(u));
            if(!(u==0 || (a>1e-8f && a<1e4f))) bad++;
            if(ed[2*i+1]==0) z++;
        }
        if(bad) atomicAdd(&det[0], bad);
        if(z)   atomicAdd(&det[1], z);
    }
    __syncthreads();
    int isf = det[0] > 64  ? 1 : 0;
    int i64 = det[1] > 512 ? 1 : 0;

    // ---- block 0: zero counts + init barrier state, release magic ----
    if(bid==0){
        for(int i=t;i<NODES;i+=256) counts[i]=0;
        if(t==0){ bar[0]=0; bar[1]=0; }
        __syncthreads();   // drains stores (vmcnt) before release
        if(t==0){
            __threadfence();
            __hip_atomic_store(&bar[2], (int)MAGIC, __ATOMIC_RELEASE, __HIP_MEMORY_SCOPE_AGENT);
        }
    }

    // ---- dense1: x@W1 + alpha1 for 8 nodes per block (overlaps block0 init) ----
    {
        struct S1 { float w1[FIN*HC1]; float av[64]; float dv[64]; float xr[8][FIN]; float hrow[8][HC1]; };
        S1* sp = reinterpret_cast<S1*>(smem);
        int n0 = bid*8;
        for(int i=t;i<FIN*HC1;i+=256) sp->w1[i] = ldf(W1,i,isf);
        if(t<64){ sp->av[t]=ldf(as1w,t,isf); sp->dv[t]=ldf(ad1w,t,isf); }
        if(t<128) sp->xr[t>>4][t&15] = ldf(x, n0*FIN + t, isf);
        __syncthreads();
        #pragma unroll
        for(int rep=0;rep<2;rep++){
            int idx = rep*256 + t;
            int r = idx>>6, c = idx&63;
            float acc = 0.f;
            #pragma unroll
            for(int k=0;k<FIN;k++) acc += sp->xr[r][k]*sp->w1[k*HC1+c];
            g1[(n0+r)*HC1 + c] = acc;
            sp->hrow[r][c] = acc;
        }
        __syncthreads();
        if(t<64){
            int ii=t>>3, h=t&7;
            float sa=0.f, sd=0.f;
            #pragma unroll
            for(int k=0;k<8;k++){ float v=sp->hrow[ii][h*8+k]; sa+=v*sp->av[h*8+k]; sd+=v*sp->dv[h*8+k]; }
            as1[(n0+ii)*8+h]=sa; ad1[(n0+ii)*8+h]=sd;
        }
        __syncthreads();
    }

    // ---- wait for counts zeroed / barrier ready ----
    if(bid!=0){
        if(t==0){
            while(__hip_atomic_load(&bar[2], __ATOMIC_ACQUIRE, __HIP_MEMORY_SCOPE_AGENT) != (int)MAGIC)
                __builtin_amdgcn_s_sleep(2);
        }
        __syncthreads();
    }

    // ---- degree count ----
    for(int e = bid*256 + t; e < E; e += NBLK*256)
        atomicAdd(&counts[edst(ed,e,E,i64)], 1);
    gbar(bar);

    // ---- exclusive scan (block 0 only) ----
    if(bid==0){
        int* ssum = reinterpret_cast<int*>(smem);
        int base = t*32;
        int loc[32]; int s = 0;
        #pragma unroll
        for(int k=0;k<32;k++){ loc[k]=s; s+=counts[base+k]; }
        ssum[t]=s;
        __syncthreads();
        for(int off=1;off<256;off<<=1){
            int v = (t>=off)? ssum[t-off] : 0;
            __syncthreads();
            ssum[t]+=v;
            __syncthreads();
        }
        int b0 = t ? ssum[t-1] : 0;
        for(int k=0;k<32;k++){ int v=b0+loc[k]; offs[base+k]=v; cursor[base+k]=v; }
        if(t==255) offs[NODES]=ssum[255];
    }
    gbar(bar);

    // ---- CSR fill ----
    for(int e = bid*256 + t; e < E; e += NBLK*256){
        int p = atomicAdd(&cursor[edst(ed,e,E,i64)], 1);
        csr[p] = esrc(ed,e,i64);
    }
    gbar(bar);

    // ---- agg1 (z1 in LDS) + dense2 + alpha2, 8 nodes per block ----
    {
        struct S2 { float avs[HC2]; float ads[HC2]; float zr[8][HC1]; };
        S2* sp = reinterpret_cast<S2*>(smem);
        int n0 = bid*8;
        for(int i=t;i<HC2;i+=256){ sp->avs[i]=ldf(as2w,i,isf); sp->ads[i]=ldf(ad2w,i,isf); }
        for(int u=0;u<2;u++){
            int n = n0 + wv*2 + u;
            int off = offs[n], deg = offs[n+1]-off, tot = deg+1;
            int h = lane&7;
            float adl = ad1[n*8+h];
            float m=-1e30f, d=0.f;
            for(int j=lane>>3;j<tot;j+=8){
                int s_ = (j<deg)?csr[off+j]:n;
                float e = lrelu(as1[s_*8+h]+adl);
                if(e>m){ d=d*__expf(m-e)+1.f; m=e; } else d+=__expf(e-m);
            }
            #pragma unroll
            for(int st=8;st<64;st<<=1){
                float m2=__shfl_xor(m,st), d2=__shfl_xor(d,st);
                float mm=fmaxf(m,m2);
                d=d*__expf(m-mm)+d2*__expf(m2-mm);
                m=mm;
            }
            float dfin = d + 1e-16f;
            int hc = lane>>3;
            float Mc=__shfl(m,hc), Dc=__shfl(dfin,hc), Ac=__shfl(adl,hc);
            float acc=0.f;
            for(int j=0;j<tot;j++){
                int s_=(j<deg)?csr[off+j]:n;
                float e=lrelu(as1[s_*8+hc]+Ac);
                acc += __expf(e-Mc)*g1[s_*HC1+lane];
            }
            sp->zr[wv*2+u][lane] = fmaxf(acc/Dc + ldf(b1,lane,isf), 0.f);
        }
        __syncthreads();
        // dense2 + alpha2 on the 8 nodes
        int c0 = t*4;
        float acc[8][4];
        #pragma unroll
        for(int i=0;i<8;i++){ acc[i][0]=0;acc[i][1]=0;acc[i][2]=0;acc[i][3]=0; }
        for(int k=0;k<HC1;k++){
            float w0,w1,w2,w3;
            if(isf){
                float4 w = *(const float4*)((const float*)W2 + (size_t)k*HC2 + c0);
                w0=w.x; w1=w.y; w2=w.z; w3=w.w;
            } else {
                ushort4 w = *(const ushort4*)((const u16*)W2 + (size_t)k*HC2 + c0);
                w0=b2f(w.x); w1=b2f(w.y); w2=b2f(w.z); w3=b2f(w.w);
            }
            #pragma unroll
            for(int i=0;i<8;i++){
                float zv = sp->zr[i][k];
                acc[i][0]+=zv*w0; acc[i][1]+=zv*w1; acc[i][2]+=zv*w2; acc[i][3]+=zv*w3;
            }
        }
        float a0=sp->avs[c0], a1=sp->avs[c0+1], a2=sp->avs[c0+2], a3=sp->avs[c0+3];
        float d0=sp->ads[c0], d1=sp->ads[c0+1], d2=sp->ads[c0+2], d3=sp->ads[c0+3];
        int hh = t>>5;
        #pragma unroll
        for(int i=0;i<8;i++){
            ushort4 o;
            o.x=f2b(acc[i][0]); o.y=f2b(acc[i][1]); o.z=f2b(acc[i][2]); o.w=f2b(acc[i][3]);
            *(ushort4*)&g2[(size_t)(n0+i)*HC2 + c0] = o;
            float pa = acc[i][0]*a0 + acc[i][1]*a1 + acc[i][2]*a2 + acc[i][3]*a3;
            float pd = acc[i][0]*d0 + acc[i][1]*d1 + acc[i][2]*d2 + acc[i][3]*d3;
            #pragma unroll
            for(int mm=1;mm<32;mm<<=1){ pa += __shfl_xor(pa,mm); pd += __shfl_xor(pd,mm); }
            if((t&31)==0){ as2[(n0+i)*8+hh]=pa; ad2[(n0+i)*8+hh]=pd; }
        }
    }
    gbar(bar);

    // ---- agg2: 2 nodes per wave ----
    {
        int n0 = bid*8;
        for(int u=0;u<2;u++){
            int n = n0 + wv*2 + u;
            int off = offs[n], deg = offs[n+1]-off, tot = deg+1;
            int h = lane&7;
            float adl = ad2[n*8+h];
            float m=-1e30f, d=0.f;
            for(int j=lane>>3;j<tot;j+=8){
                int s_ = (j<deg)?csr[off+j]:n;
                float e = lrelu(as2[s_*8+h]+adl);
                if(e>m){ d=d*__expf(m-e)+1.f; m=e; } else d+=__expf(e-m);
            }
            #pragma unroll
            for(int st=8;st<64;st<<=1){
                float m2=__shfl_xor(m,st), d2=__shfl_xor(d,st);
                float mm=fmaxf(m,m2);
                d=d*__expf(m-mm)+d2*__expf(m2-mm);
                m=mm;
            }
            float dfin = d + 1e-16f;
            float Mq[4], Dq[4], Aq[4];
            int hq[4];
            #pragma unroll
            for(int q=0;q<4;q++){
                hq[q] = q*2 + (lane>>5);
                Mq[q] = __shfl(m,    hq[q]);
                Dq[q] = __shfl(dfin, hq[q]);
                Aq[q] = __shfl(adl,  hq[q]);
            }
            float acc[4][4];
            #pragma unroll
            for(int q=0;q<4;q++){ acc[q][0]=0;acc[q][1]=0;acc[q][2]=0;acc[q][3]=0; }
            for(int j=0;j<tot;j++){
                int s_=(j<deg)?csr[off+j]:n;
                const u16* gp = g2 + (size_t)s_*HC2;
                #pragma unroll
                for(int q=0;q<4;q++){
                    float e = lrelu(as2[s_*8+hq[q]] + Aq[q]);
                    float w = __expf(e - Mq[q]);
                    ushort4 v = *(const ushort4*)&gp[q*256 + lane*4];
                    acc[q][0] += w*b2f(v.x); acc[q][1] += w*b2f(v.y);
                    acc[q][2] += w*b2f(v.z); acc[q][3] += w*b2f(v.w);
                }
            }
            #pragma unroll
            for(int q=0;q<4;q++){
                int c0 = q*256 + lane*4;
                ushort4 o;
                o.x = f2b(fmaxf(acc[q][0]/Dq[q] + ldf(b2,c0+0,isf), 0.f));
                o.y = f2b(fmaxf(acc[q][1]/Dq[q] + ldf(b2,c0+1,isf), 0.f));
                o.z = f2b(fmaxf(acc[q][2]/Dq[q] + ldf(b2,c0+2,isf), 0.f));
                o.w = f2b(fmaxf(acc[q][3]/Dq[q] + ldf(b2,c0+3,isf), 0.f));
                *(ushort4*)&hbf[(size_t)n*HC2 + c0] = o;
            }
        }
    }
    gbar(bar);

    // ---- head GEMVs: all 4096 waves do v1 (ITERS=32), then adv (ITERS=8) ----
    {
        int wid = bid*4 + wv;
        gemv_part<64,4096>(v1w, hbf, s1, wid, lane, isf);
        gemv_part<16,4096>(advw, hbf, s2, wid, lane, isf);
    }
    gbar(bar);

    // ---- reduce partials (blocks 0..9) ----
    if(bid<10){
        float* red = reinterpret_cast<float*>(smem);
        int ph=t>>6, ln=t&63;
        float a=0.f;
        if(bid<8){
            int o = bid*64+ln;
            for(int p=ph;p<4096;p+=4) a += s1[(size_t)p*512 + o];
            red[t]=a; __syncthreads();
            if(t<64) v1a[bid*64+t] = red[t]+red[64+t]+red[128+t]+red[192+t];
        } else {
            int o = (bid-8)*64+ln;
            for(int p=ph;p<4096;p+=4) a += s2[(size_t)p*128 + o];
            red[t]=a; __syncthreads();
            if(t<64) adva[(bid-8)*64+t] = red[t]+red[64+t]+red[128+t]+red[192+t];
        }
        __syncthreads();
    }
    gbar(bar);

    // ---- value MLP + dueling combine (block 0) ----
    if(bid==0){
        struct S3 { float v1[8][64]; float v2[8][64]; float adv[128]; float v3[8]; };
        S3* sp = reinterpret_cast<S3*>(smem);
        #pragma unroll
        for(int rep=0;rep<2;rep++){
            int idx=rep*256+t; int b=idx>>6, j=idx&63;
            sp->v1[b][j] = fmaxf(v1a[idx] + ldf(v1b,j,isf), 0.f);
        }
        if(t<128) sp->adv[t] = fmaxf(adva[t] + ldf(advb,t&15,isf), 0.f);
        __syncthreads();
        #pragma unroll
        for(int rep=0;rep<2;rep++){
            int idx=rep*256+t; int b=idx>>6, j=idx&63;
            float a=0.f;
            for(int k=0;k<64;k++) a += sp->v1[b][k]*ldf(v2w,k*64+j,isf);
            sp->v2[b][j] = fmaxf(a + ldf(b2v,j,isf), 0.f);
        }
        __syncthreads();
        if(t<8){
            float a=0.f;
            for(int k=0;k<64;k++) a += sp->v2[t][k]*ldf(v3w,k,isf);
            sp->v3[t] = a + ldf(b3v,0,isf);
        }
        __syncthreads();
        if(t<128){
            int b=t>>4, r=(t>>2)&3;
            int base = b*16 + r*4;
            float mm = 0.25f*(sp->adv[base]+sp->adv[base+1]+sp->adv[base+2]+sp->adv[base+3]);
            float val = sp->v3[b] + sp->adv[t] - mm;
            if(isf) ((float*)out)[t] = val;
            else    ((u16*)out)[t]   = f2b(val);
        }
        if(t==0) __hip_atomic_store(&bar[2], 0, __ATOMIC_RELAXED, __HIP_MEMORY_SCOPE_AGENT);
    }
}

// ---------- host ----------
extern "C" void kernel_launch(void* const* d_in, const int* in_sizes, int n_in,
                              void* d_out, int out_size, void* d_ws, size_t ws_size,
                              hipStream_t stream){
    const void* x    = d_in[0];
    const int*  edge = (const int*)d_in[1];
    const int E = in_sizes[1]/2;
    const void* W1   = d_in[2];
    const void* as1w = d_in[3];
    const void* ad1w = d_in[4];
    const void* b1   = d_in[5];
    const void* W2   = d_in[6];
    const void* as2w = d_in[7];
    const void* ad2w = d_in[8];
    const void* b2   = d_in[9];
    const void* advw = d_in[10];
    const void* advb = d_in[11];
    const void* v1w  = d_in[12];
    const void* v1b  = d_in[13];
    const void* v2w  = d_in[14];
    const void* v2b  = d_in[15];
    const void* v3w  = d_in[16];
    const void* v3b  = d_in[17];

    char* wsp = (char*)d_ws;
    size_t o = 0;
    auto alloc = [&](size_t bytes)->char*{
        char* p = wsp + o;
        o = (o + bytes + 255) & ~(size_t)255;
        return p;
    };
    int*   counts = (int*)  alloc(NODES*4);
    int*   offs   = (int*)  alloc((NODES+8)*4);
    int*   cursor = (int*)  alloc(NODES*4);
    int*   csr    = (int*)  alloc((size_t)E*4);
    float* g1     = (float*)alloc((size_t)NODES*HC1*4);
    float* as1    = (float*)alloc((size_t)NODES*8*4);
    float* ad1    = (float*)alloc((size_t)NODES*8*4);
    u16*   g2     = (u16*)  alloc((size_t)NODES*HC2*2);
    float* as2    = (float*)alloc((size_t)NODES*8*4);
    float* ad2    = (float*)alloc((size_t)NODES*8*4);
    u16*   hbf    = (u16*)  alloc((size_t)NODES*HC2*2);
    float* s1     = (float*)alloc((size_t)4096*512*4);   // 8 MB
    float* s2     = (float*)alloc((size_t)4096*128*4);   // 2 MB
    float* v1a    = (float*)alloc(512*4);
    float* adva   = (float*)alloc(128*4);
    int*   bar    = (int*)  alloc(256);

    k_mega<<<NBLK, 256, 0, stream>>>(
        x, edge, E,
        W1, as1w, ad1w, b1,
        W2, as2w, ad2w, b2,
        advw, advb,
        v1w, v1b, v2w, v2b, v3w, v3b,
        counts, offs, cursor, csr,
        g1, as1, ad1,
        g2, as2, ad2, hbf,
        s1, s2, v1a, adva,
        bar, d_out);
}

// Round 3
// 1390.352 us; speedup vs baseline: 5.3013x; 5.3013x over previous
//
#include <hip/hip_runtime.h>
#include <stdint.h>

#define NODES   8192
#define FIN     16
#define HC1     64
#define HC2     1024
#define DTOT    1048576
#define NEG     0.2f
#define NBLK    1024
#define MAGIC   0x5A17C0DE

typedef unsigned short u16;
typedef float f4v __attribute__((ext_vector_type(4)));
typedef unsigned short u4v __attribute__((ext_vector_type(4)));

__device__ __forceinline__ float b2f(u16 s){ return __uint_as_float(((unsigned)s)<<16); }
__device__ __forceinline__ u16 f2b(float f){
    unsigned u = __float_as_uint(f);
    unsigned r = u + 0x7fffu + ((u>>16)&1u);
    return (u16)(r>>16);
}
__device__ __forceinline__ float lrelu(float x){ return x > 0.f ? x : NEG*x; }
__device__ __forceinline__ float ldf(const void* p, long i, int isf){
    return isf ? ((const float*)p)[i] : b2f(((const u16*)p)[i]);
}
__device__ __forceinline__ int esrc(const int* e, int i, int i64){ return i64 ? e[2*i] : e[i]; }
__device__ __forceinline__ int edst(const int* e, int i, int E, int i64){ return i64 ? e[2*(E+i)] : e[E+i]; }

// ---- device-scope generation barrier: RELAXED polling, one acquire fence on exit ----
__device__ __forceinline__ void gbar(int* bar){
    __syncthreads();
    if(threadIdx.x==0){
        int g = __hip_atomic_load(&bar[1], __ATOMIC_RELAXED, __HIP_MEMORY_SCOPE_AGENT);
        int a = __hip_atomic_fetch_add(&bar[0], 1, __ATOMIC_ACQ_REL, __HIP_MEMORY_SCOPE_AGENT);
        if(a == NBLK-1){
            __hip_atomic_store(&bar[0], 0, __ATOMIC_RELAXED, __HIP_MEMORY_SCOPE_AGENT);
            __hip_atomic_store(&bar[1], g+1, __ATOMIC_RELEASE, __HIP_MEMORY_SCOPE_AGENT);
        } else {
            while(__hip_atomic_load(&bar[1], __ATOMIC_RELAXED, __HIP_MEMORY_SCOPE_AGENT) == g)
                __builtin_amdgcn_s_sleep(8);
            __builtin_amdgcn_fence(__ATOMIC_ACQUIRE, "agent");
        }
    }
    __syncthreads();
}

// ---- fused head GEMV partial (per wave); writes TRANSPOSED partials s[col*4096+wid] ----
template<int COLS, int NW>
__device__ __forceinline__ void gemv_part(const void* __restrict__ W, const u16* __restrict__ hbf,
        float* __restrict__ scratch, int wid, int lane, int isf){
    const int GR    = COLS/8;
    const int KSTEP = 64/GR;
    const int ITERS = DTOT/(NW*KSTEP);
    int cg  = (lane % GR)*8;
    int kof = lane / GR;
    float acc[8][8];
    #pragma unroll
    for(int b=0;b<8;b++)
        #pragma unroll
        for(int c=0;c<8;c++) acc[b][c]=0.f;
    for(int it=0; it<ITERS; ++it){
        int k0 = (it*NW + wid)*KSTEP + kof;
        float wv0[8];
        if(isf){
            f4v a0 = __builtin_nontemporal_load((const f4v*)((const float*)W + (size_t)k0*COLS + cg));
            f4v b0 = __builtin_nontemporal_load((const f4v*)((const float*)W + (size_t)k0*COLS + cg + 4));
            wv0[0]=a0.x;wv0[1]=a0.y;wv0[2]=a0.z;wv0[3]=a0.w;wv0[4]=b0.x;wv0[5]=b0.y;wv0[6]=b0.z;wv0[7]=b0.w;
        } else {
            u4v a0 = __builtin_nontemporal_load((const u4v*)((const u16*)W + (size_t)k0*COLS + cg));
            u4v b0 = __builtin_nontemporal_load((const u4v*)((const u16*)W + (size_t)k0*COLS + cg + 4));
            wv0[0]=b2f(a0.x);wv0[1]=b2f(a0.y);wv0[2]=b2f(a0.z);wv0[3]=b2f(a0.w);
            wv0[4]=b2f(b0.x);wv0[5]=b2f(b0.y);wv0[6]=b2f(b0.z);wv0[7]=b2f(b0.w);
        }
        float hv0[8];
        #pragma unroll
        for(int b=0;b<8;b++) hv0[b] = b2f(hbf[(size_t)b*DTOT + k0]);
        #pragma unroll
        for(int b=0;b<8;b++)
            #pragma unroll
            for(int c=0;c<8;c++) acc[b][c] += hv0[b]*wv0[c];
    }
    #pragma unroll
    for(int m=GR;m<64;m<<=1){
        #pragma unroll
        for(int b=0;b<8;b++)
            #pragma unroll
            for(int c=0;c<8;c++) acc[b][c] += __shfl_xor(acc[b][c], m);
    }
    int q = lane / GR;
    if(q < 8){
        #pragma unroll
        for(int c=0;c<8;c++)
            scratch[(size_t)(q*COLS + cg + c)*4096 + wid] = acc[q][c];
    }
}

// =================== the whole pipeline in one dispatch ===================
__global__ __launch_bounds__(256,4) void k_mega(
        const void* __restrict__ x, const int* __restrict__ ed, int E,
        const void* __restrict__ W1, const void* __restrict__ as1w, const void* __restrict__ ad1w,
        const void* __restrict__ b1,
        const void* __restrict__ W2, const void* __restrict__ as2w, const void* __restrict__ ad2w,
        const void* __restrict__ b2,
        const void* __restrict__ advw, const void* __restrict__ advb,
        const void* __restrict__ v1w, const void* __restrict__ v1b,
        const void* __restrict__ v2w, const void* __restrict__ b2v,
        const void* __restrict__ v3w, const void* __restrict__ b3v,
        int* counts, int* offs, int* cursor, int* csr,
        float* g1, float* as1, float* ad1,
        u16* g2, float* as2, float* ad2, u16* hbf,
        float* s1, float* s2, float* v1a, float* adva,
        int* bar, void* out){
    int t = threadIdx.x, bid = blockIdx.x;
    int lane = t & 63, wv = t >> 6;
    __shared__ int det[2];
    __shared__ __align__(16) char smem[10496];

    // ---- per-block dtype / index-width detection (no cross-block dep) ----
    if(t<2) det[t]=0;
    __syncthreads();
    {
        int bad=0, z=0;
        const u16* xs = (const u16*)x;
        for(int i=t;i<1024;i+=256){
            u16 u = xs[i];
            float a = fabsf(b2f(u));
            if(!(u==0 || (a>1e-8f && a<1e4f))) bad++;
            if(ed[2*i+1]==0) z++;
        }
        if(bad) atomicAdd(&det[0], bad);
        if(z)   atomicAdd(&det[1], z);
    }
    __syncthreads();
    int isf = det[0] > 64  ? 1 : 0;
    int i64 = det[1] > 512 ? 1 : 0;

    // ---- block 0: zero counts + init barrier state, release magic ----
    if(bid==0){
        for(int i=t;i<NODES;i+=256) counts[i]=0;
        if(t==0){
            __hip_atomic_store(&bar[0], 0, __ATOMIC_RELAXED, __HIP_MEMORY_SCOPE_AGENT);
            __hip_atomic_store(&bar[1], 0, __ATOMIC_RELAXED, __HIP_MEMORY_SCOPE_AGENT);
        }
        __syncthreads();
        if(t==0)
            __hip_atomic_store(&bar[2], (int)MAGIC, __ATOMIC_RELEASE, __HIP_MEMORY_SCOPE_AGENT);
    }

    // ---- dense1: x@W1 + alpha1 for 8 nodes per block (overlaps block0 init) ----
    {
        struct S1 { float w1[FIN*HC1]; float av[64]; float dv[64]; float xr[8][FIN]; float hrow[8][HC1]; };
        S1* sp = reinterpret_cast<S1*>(smem);
        int n0 = bid*8;
        for(int i=t;i<FIN*HC1;i+=256) sp->w1[i] = ldf(W1,i,isf);
        if(t<64){ sp->av[t]=ldf(as1w,t,isf); sp->dv[t]=ldf(ad1w,t,isf); }
        if(t<128) sp->xr[t>>4][t&15] = ldf(x, n0*FIN + t, isf);
        __syncthreads();
        #pragma unroll
        for(int rep=0;rep<2;rep++){
            int idx = rep*256 + t;
            int r = idx>>6, c = idx&63;
            float acc = 0.f;
            #pragma unroll
            for(int k=0;k<FIN;k++) acc += sp->xr[r][k]*sp->w1[k*HC1+c];
            g1[(n0+r)*HC1 + c] = acc;
            sp->hrow[r][c] = acc;
        }
        __syncthreads();
        if(t<64){
            int ii=t>>3, h=t&7;
            float sa=0.f, sd=0.f;
            #pragma unroll
            for(int k=0;k<8;k++){ float v=sp->hrow[ii][h*8+k]; sa+=v*sp->av[h*8+k]; sd+=v*sp->dv[h*8+k]; }
            as1[(n0+ii)*8+h]=sa; ad1[(n0+ii)*8+h]=sd;
        }
        __syncthreads();
    }

    // ---- wait for counts zeroed / barrier ready (relaxed poll + one fence) ----
    if(bid!=0){
        if(t==0){
            while(__hip_atomic_load(&bar[2], __ATOMIC_RELAXED, __HIP_MEMORY_SCOPE_AGENT) != (int)MAGIC)
                __builtin_amdgcn_s_sleep(8);
            __builtin_amdgcn_fence(__ATOMIC_ACQUIRE, "agent");
        }
        __syncthreads();
    }

    // ---- degree count ----
    for(int e = bid*256 + t; e < E; e += NBLK*256)
        atomicAdd(&counts[edst(ed,e,E,i64)], 1);
    gbar(bar);

    // ---- exclusive scan (block 0 only) ----
    if(bid==0){
        int* ssum = reinterpret_cast<int*>(smem);
        int base = t*32;
        int loc[32]; int s = 0;
        #pragma unroll
        for(int k=0;k<32;k++){ loc[k]=s; s+=counts[base+k]; }
        ssum[t]=s;
        __syncthreads();
        for(int off=1;off<256;off<<=1){
            int v = (t>=off)? ssum[t-off] : 0;
            __syncthreads();
            ssum[t]+=v;
            __syncthreads();
        }
        int b0 = t ? ssum[t-1] : 0;
        #pragma unroll
        for(int k=0;k<32;k++){ int v=b0+loc[k]; offs[base+k]=v; cursor[base+k]=v; }
        if(t==255) offs[NODES]=ssum[255];
    }
    gbar(bar);

    // ---- CSR fill ----
    for(int e = bid*256 + t; e < E; e += NBLK*256){
        int p = atomicAdd(&cursor[edst(ed,e,E,i64)], 1);
        csr[p] = esrc(ed,e,i64);
    }
    gbar(bar);

    // ---- agg1 (z1 in LDS) + dense2 + alpha2, 8 nodes per block ----
    {
        struct S2 { float avs[HC2]; float ads[HC2]; float zr[8][HC1]; };
        S2* sp = reinterpret_cast<S2*>(smem);
        int n0 = bid*8;
        for(int i=t;i<HC2;i+=256){ sp->avs[i]=ldf(as2w,i,isf); sp->ads[i]=ldf(ad2w,i,isf); }
        for(int u=0;u<2;u++){
            int n = n0 + wv*2 + u;
            int off = offs[n], deg = offs[n+1]-off, tot = deg+1;
            int h = lane&7;
            float adl = ad1[n*8+h];
            float m=-1e30f, d=0.f;
            for(int j=lane>>3;j<tot;j+=8){
                int s_ = (j<deg)?csr[off+j]:n;
                float e = lrelu(as1[s_*8+h]+adl);
                if(e>m){ d=d*__expf(m-e)+1.f; m=e; } else d+=__expf(e-m);
            }
            #pragma unroll
            for(int st=8;st<64;st<<=1){
                float m2=__shfl_xor(m,st), d2=__shfl_xor(d,st);
                float mm=fmaxf(m,m2);
                d=d*__expf(m-mm)+d2*__expf(m2-mm);
                m=mm;
            }
            float dfin = d + 1e-16f;
            int hc = lane>>3;
            float Mc=__shfl(m,hc), Dc=__shfl(dfin,hc), Ac=__shfl(adl,hc);
            float acc=0.f;
            for(int j=0;j<tot;j++){
                int s_=(j<deg)?csr[off+j]:n;
                float e=lrelu(as1[s_*8+hc]+Ac);
                acc += __expf(e-Mc)*g1[s_*HC1+lane];
            }
            sp->zr[wv*2+u][lane] = fmaxf(acc/Dc + ldf(b1,lane,isf), 0.f);
        }
        __syncthreads();
        // dense2 + alpha2 on the 8 nodes
        int c0 = t*4;
        float acc[8][4];
        #pragma unroll
        for(int i=0;i<8;i++){ acc[i][0]=0;acc[i][1]=0;acc[i][2]=0;acc[i][3]=0; }
        for(int k=0;k<HC1;k++){
            float w0,w1,w2,w3;
            if(isf){
                float4 w = *(const float4*)((const float*)W2 + (size_t)k*HC2 + c0);
                w0=w.x; w1=w.y; w2=w.z; w3=w.w;
            } else {
                ushort4 w = *(const ushort4*)((const u16*)W2 + (size_t)k*HC2 + c0);
                w0=b2f(w.x); w1=b2f(w.y); w2=b2f(w.z); w3=b2f(w.w);
            }
            #pragma unroll
            for(int i=0;i<8;i++){
                float zv = sp->zr[i][k];
                acc[i][0]+=zv*w0; acc[i][1]+=zv*w1; acc[i][2]+=zv*w2; acc[i][3]+=zv*w3;
            }
        }
        float a0=sp->avs[c0], a1=sp->avs[c0+1], a2=sp->avs[c0+2], a3=sp->avs[c0+3];
        float d0=sp->ads[c0], d1=sp->ads[c0+1], d2=sp->ads[c0+2], d3=sp->ads[c0+3];
        int hh = t>>5;
        #pragma unroll
        for(int i=0;i<8;i++){
            ushort4 o;
            o.x=f2b(acc[i][0]); o.y=f2b(acc[i][1]); o.z=f2b(acc[i][2]); o.w=f2b(acc[i][3]);
            *(ushort4*)&g2[(size_t)(n0+i)*HC2 + c0] = o;
            float pa = acc[i][0]*a0 + acc[i][1]*a1 + acc[i][2]*a2 + acc[i][3]*a3;
            float pd = acc[i][0]*d0 + acc[i][1]*d1 + acc[i][2]*d2 + acc[i][3]*d3;
            #pragma unroll
            for(int mm=1;mm<32;mm<<=1){ pa += __shfl_xor(pa,mm); pd += __shfl_xor(pd,mm); }
            if((t&31)==0){ as2[(n0+i)*8+hh]=pa; ad2[(n0+i)*8+hh]=pd; }
        }
    }
    gbar(bar);

    // ---- agg2: 2 nodes per wave ----
    {
        int n0 = bid*8;
        for(int u=0;u<2;u++){
            int n = n0 + wv*2 + u;
            int off = offs[n], deg = offs[n+1]-off, tot = deg+1;
            int h = lane&7;
            float adl = ad2[n*8+h];
            float m=-1e30f, d=0.f;
            for(int j=lane>>3;j<tot;j+=8){
                int s_ = (j<deg)?csr[off+j]:n;
                float e = lrelu(as2[s_*8+h]+adl);
                if(e>m){ d=d*__expf(m-e)+1.f; m=e; } else d+=__expf(e-m);
            }
            #pragma unroll
            for(int st=8;st<64;st<<=1){
                float m2=__shfl_xor(m,st), d2=__shfl_xor(d,st);
                float mm=fmaxf(m,m2);
                d=d*__expf(m-mm)+d2*__expf(m2-mm);
                m=mm;
            }
            float dfin = d + 1e-16f;
            float Mq[4], Dq[4], Aq[4];
            int hq[4];
            #pragma unroll
            for(int q=0;q<4;q++){
                hq[q] = q*2 + (lane>>5);
                Mq[q] = __shfl(m,    hq[q]);
                Dq[q] = __shfl(dfin, hq[q]);
                Aq[q] = __shfl(adl,  hq[q]);
            }
            float acc[4][4];
            #pragma unroll
            for(int q=0;q<4;q++){ acc[q][0]=0;acc[q][1]=0;acc[q][2]=0;acc[q][3]=0; }
            for(int j=0;j<tot;j++){
                int s_=(j<deg)?csr[off+j]:n;
                const u16* gp = g2 + (size_t)s_*HC2;
                #pragma unroll
                for(int q=0;q<4;q++){
                    float e = lrelu(as2[s_*8+hq[q]] + Aq[q]);
                    float w = __expf(e - Mq[q]);
                    ushort4 v = *(const ushort4*)&gp[q*256 + lane*4];
                    acc[q][0] += w*b2f(v.x); acc[q][1] += w*b2f(v.y);
                    acc[q][2] += w*b2f(v.z); acc[q][3] += w*b2f(v.w);
                }
            }
            #pragma unroll
            for(int q=0;q<4;q++){
                int c0 = q*256 + lane*4;
                ushort4 o;
                o.x = f2b(fmaxf(acc[q][0]/Dq[q] + ldf(b2,c0+0,isf), 0.f));
                o.y = f2b(fmaxf(acc[q][1]/Dq[q] + ldf(b2,c0+1,isf), 0.f));
                o.z = f2b(fmaxf(acc[q][2]/Dq[q] + ldf(b2,c0+2,isf), 0.f));
                o.w = f2b(fmaxf(acc[q][3]/Dq[q] + ldf(b2,c0+3,isf), 0.f));
                *(ushort4*)&hbf[(size_t)n*HC2 + c0] = o;
            }
        }
    }
    gbar(bar);

    // ---- head GEMVs: all 4096 waves do v1 (ITERS=32), then adv (ITERS=8) ----
    {
        int wid = bid*4 + wv;
        gemv_part<64,4096>(v1w, hbf, s1, wid, lane, isf);
        gemv_part<16,4096>(advw, hbf, s2, wid, lane, isf);
    }
    gbar(bar);

    // ---- reduce partials: 640 columns, one wave each (blocks 0..159) ----
    if(bid<160){
        int col = bid*4 + wv;
        const float* src = (col<512) ? (s1 + (size_t)col*4096) : (s2 + (size_t)(col-512)*4096);
        float a=0.f;
        for(int it=0; it<16; ++it){
            float4 v = *(const float4*)(src + it*256 + lane*4);
            a += v.x+v.y+v.z+v.w;
        }
        #pragma unroll
        for(int m=1;m<64;m<<=1) a += __shfl_xor(a,m);
        if(lane==0){
            if(col<512) v1a[col]=a; else adva[col-512]=a;
        }
    }
    gbar(bar);

    // ---- value MLP + dueling combine (block 0) ----
    if(bid==0){
        struct S3 { float v1[8][64]; float v2[8][64]; float adv[128]; float v3[8]; };
        S3* sp = reinterpret_cast<S3*>(smem);
        #pragma unroll
        for(int rep=0;rep<2;rep++){
            int idx=rep*256+t; int b=idx>>6, j=idx&63;
            sp->v1[b][j] = fmaxf(v1a[idx] + ldf(v1b,j,isf), 0.f);
        }
        if(t<128) sp->adv[t] = fmaxf(adva[t] + ldf(advb,t&15,isf), 0.f);
        __syncthreads();
        #pragma unroll
        for(int rep=0;rep<2;rep++){
            int idx=rep*256+t; int b=idx>>6, j=idx&63;
            float a=0.f;
            for(int k=0;k<64;k++) a += sp->v1[b][k]*ldf(v2w,k*64+j,isf);
            sp->v2[b][j] = fmaxf(a + ldf(b2v,j,isf), 0.f);
        }
        __syncthreads();
        if(t<8){
            float a=0.f;
            for(int k=0;k<64;k++) a += sp->v2[t][k]*ldf(v3w,k,isf);
            sp->v3[t] = a + ldf(b3v,0,isf);
        }
        __syncthreads();
        if(t<128){
            int b=t>>4, r=(t>>2)&3;
            int base = b*16 + r*4;
            float mm = 0.25f*(sp->adv[base]+sp->adv[base+1]+sp->adv[base+2]+sp->adv[base+3]);
            float val = sp->v3[b] + sp->adv[t] - mm;
            if(isf) ((float*)out)[t] = val;
            else    ((u16*)out)[t]   = f2b(val);
        }
        if(t==0) __hip_atomic_store(&bar[2], 0, __ATOMIC_RELAXED, __HIP_MEMORY_SCOPE_AGENT);
    }
}

// ---------- host ----------
extern "C" void kernel_launch(void* const* d_in, const int* in_sizes, int n_in,
                              void* d_out, int out_size, void* d_ws, size_t ws_size,
                              hipStream_t stream){
    const void* x    = d_in[0];
    const int*  edge = (const int*)d_in[1];
    const int E = in_sizes[1]/2;
    const void* W1   = d_in[2];
    const void* as1w = d_in[3];
    const void* ad1w = d_in[4];
    const void* b1   = d_in[5];
    const void* W2   = d_in[6];
    const void* as2w = d_in[7];
    const void* ad2w = d_in[8];
    const void* b2   = d_in[9];
    const void* advw = d_in[10];
    const void* advb = d_in[11];
    const void* v1w  = d_in[12];
    const void* v1b  = d_in[13];
    const void* v2w  = d_in[14];
    const void* v2b  = d_in[15];
    const void* v3w  = d_in[16];
    const void* v3b  = d_in[17];

    char* wsp = (char*)d_ws;
    size_t o = 0;
    auto alloc = [&](size_t bytes)->char*{
        char* p = wsp + o;
        o = (o + bytes + 255) & ~(size_t)255;
        return p;
    };
    int*   counts = (int*)  alloc(NODES*4);
    int*   offs   = (int*)  alloc((NODES+8)*4);
    int*   cursor = (int*)  alloc(NODES*4);
    int*   csr    = (int*)  alloc((size_t)E*4);
    float* g1     = (float*)alloc((size_t)NODES*HC1*4);
    float* as1    = (float*)alloc((size_t)NODES*8*4);
    float* ad1    = (float*)alloc((size_t)NODES*8*4);
    u16*   g2     = (u16*)  alloc((size_t)NODES*HC2*2);
    float* as2    = (float*)alloc((size_t)NODES*8*4);
    float* ad2    = (float*)alloc((size_t)NODES*8*4);
    u16*   hbf    = (u16*)  alloc((size_t)NODES*HC2*2);
    float* s1     = (float*)alloc((size_t)512*4096*4);   // 8 MB (transposed: [col][wid])
    float* s2     = (float*)alloc((size_t)128*4096*4);   // 2 MB (transposed)
    float* v1a    = (float*)alloc(512*4);
    float* adva   = (float*)alloc(128*4);
    int*   bar    = (int*)  alloc(256);

    k_mega<<<NBLK, 256, 0, stream>>>(
        x, edge, E,
        W1, as1w, ad1w, b1,
        W2, as2w, ad2w, b2,
        advw, advb,
        v1w, v1b, v2w, v2b, v3w, v3b,
        counts, offs, cursor, csr,
        g1, as1, ad1,
        g2, as2, ad2, hbf,
        s1, s2, v1a, adva,
        bar, d_out);
}

// Round 4
// 862.145 us; speedup vs baseline: 8.5493x; 1.6127x over previous
//
#include <hip/hip_runtime.h>
#include <stdint.h>

#define NODES   8192
#define FIN     16
#define HC1     64
#define HC2     1024
#define DTOT    1048576
#define NEG     0.2f
#define NBLK    1024
#define MAGIC   0x5A17C0DE

typedef unsigned short u16;
typedef float f4v __attribute__((ext_vector_type(4)));
typedef unsigned short u4v __attribute__((ext_vector_type(4)));

__device__ __forceinline__ float b2f(u16 s){ return __uint_as_float(((unsigned)s)<<16); }
__device__ __forceinline__ u16 f2b(float f){
    unsigned u = __float_as_uint(f);
    unsigned r = u + 0x7fffu + ((u>>16)&1u);
    return (u16)(r>>16);
}
__device__ __forceinline__ float lrelu(float x){ return x > 0.f ? x : NEG*x; }
__device__ __forceinline__ float ldf(const void* p, long i, int isf){
    return isf ? ((const float*)p)[i] : b2f(((const u16*)p)[i]);
}
__device__ __forceinline__ int esrc(const int* e, int i, int i64){ return i64 ? e[2*i] : e[i]; }
__device__ __forceinline__ int edst(const int* e, int i, int E, int i64){ return i64 ? e[2*(E+i)] : e[E+i]; }

// ---- barrier state layout (ints): [0]=ready magic, [16]=gen, [32]=root, [48]=minicnt,
// ---- [64+g*16] = leaf counter for group g (g = bid>>5, 32 groups). All monotonic.
__device__ __forceinline__ void garrive(int* bar, int bid){
    __builtin_amdgcn_fence(__ATOMIC_RELEASE, "agent");
    int a = __hip_atomic_fetch_add(&bar[64 + ((bid>>5)<<4)], 1, __ATOMIC_RELAXED, __HIP_MEMORY_SCOPE_AGENT);
    if((a & 31) == 31){
        int r = __hip_atomic_fetch_add(&bar[32], 1, __ATOMIC_RELAXED, __HIP_MEMORY_SCOPE_AGENT);
        if((r & 31) == 31)
            __hip_atomic_fetch_add(&bar[16], 1, __ATOMIC_RELEASE, __HIP_MEMORY_SCOPE_AGENT);
    }
}
__device__ __forceinline__ void gwait(int* bar, int phase){
    while(__hip_atomic_load(&bar[16], __ATOMIC_RELAXED, __HIP_MEMORY_SCOPE_AGENT) < phase)
        __builtin_amdgcn_s_sleep(4);
    __builtin_amdgcn_fence(__ATOMIC_ACQUIRE, "agent");
}

// ---- fused head GEMV partial (per wave); result goes to the block's LDS row ----
template<int COLS, int NW>
__device__ __forceinline__ void gemv_part(const void* __restrict__ W, const u16* __restrict__ hbf,
        float* __restrict__ ldsrow, int base, int wid, int lane, int isf){
    const int GR    = COLS/8;
    const int KSTEP = 64/GR;
    const int ITERS = DTOT/(NW*KSTEP);
    int cg  = (lane % GR)*8;
    int kof = lane / GR;
    float acc[8][8];
    #pragma unroll
    for(int b=0;b<8;b++)
        #pragma unroll
        for(int c=0;c<8;c++) acc[b][c]=0.f;
    for(int it=0; it<ITERS; ++it){
        int k0 = (it*NW + wid)*KSTEP + kof;
        float wv0[8];
        if(isf){
            f4v a0 = __builtin_nontemporal_load((const f4v*)((const float*)W + (size_t)k0*COLS + cg));
            f4v b0 = __builtin_nontemporal_load((const f4v*)((const float*)W + (size_t)k0*COLS + cg + 4));
            wv0[0]=a0.x;wv0[1]=a0.y;wv0[2]=a0.z;wv0[3]=a0.w;wv0[4]=b0.x;wv0[5]=b0.y;wv0[6]=b0.z;wv0[7]=b0.w;
        } else {
            u4v a0 = __builtin_nontemporal_load((const u4v*)((const u16*)W + (size_t)k0*COLS + cg));
            u4v b0 = __builtin_nontemporal_load((const u4v*)((const u16*)W + (size_t)k0*COLS + cg + 4));
            wv0[0]=b2f(a0.x);wv0[1]=b2f(a0.y);wv0[2]=b2f(a0.z);wv0[3]=b2f(a0.w);
            wv0[4]=b2f(b0.x);wv0[5]=b2f(b0.y);wv0[6]=b2f(b0.z);wv0[7]=b2f(b0.w);
        }
        float hv0[8];
        #pragma unroll
        for(int b=0;b<8;b++) hv0[b] = b2f(hbf[(size_t)b*DTOT + k0]);
        #pragma unroll
        for(int b=0;b<8;b++)
            #pragma unroll
            for(int c=0;c<8;c++) acc[b][c] += hv0[b]*wv0[c];
    }
    #pragma unroll
    for(int m=GR;m<64;m<<=1){
        #pragma unroll
        for(int b=0;b<8;b++)
            #pragma unroll
            for(int c=0;c<8;c++) acc[b][c] += __shfl_xor(acc[b][c], m);
    }
    int q = lane / GR;
    if(q < 8){
        #pragma unroll
        for(int c=0;c<8;c++) ldsrow[base + q*COLS + cg + c] = acc[q][c];
    }
}

// =================== the whole pipeline in one dispatch ===================
__global__ __launch_bounds__(256,4) void k_mega(
        const void* __restrict__ x, const int* __restrict__ ed, int E,
        const void* __restrict__ W1, const void* __restrict__ as1w, const void* __restrict__ ad1w,
        const void* __restrict__ b1,
        const void* __restrict__ W2, const void* __restrict__ as2w, const void* __restrict__ ad2w,
        const void* __restrict__ b2,
        const void* __restrict__ advw, const void* __restrict__ advb,
        const void* __restrict__ v1w, const void* __restrict__ v1b,
        const void* __restrict__ v2w, const void* __restrict__ b2v,
        const void* __restrict__ v3w, const void* __restrict__ b3v,
        int* counts, int* offs, int* cursor, int* csr,
        float* g1, float* as1, float* ad1,
        u16* g2, float* as2, float* ad2, u16* hbf,
        float* s1b, float* v1a, float* adva,
        int* bar, void* out){
    int t = threadIdx.x, bid = blockIdx.x;
    int lane = t & 63, wv = t >> 6;
    __shared__ int det[2];
    __shared__ __align__(16) char smem[10496];

    // ---- per-block dtype / index-width detection ----
    if(t<2) det[t]=0;
    __syncthreads();
    {
        int bad=0, z=0;
        const u16* xs = (const u16*)x;
        for(int i=t;i<1024;i+=256){
            u16 u = xs[i];
            float a = fabsf(b2f(u));
            if(!(u==0 || (a>1e-8f && a<1e4f))) bad++;
            if(ed[2*i+1]==0) z++;
        }
        if(bad) atomicAdd(&det[0], bad);
        if(z)   atomicAdd(&det[1], z);
    }
    __syncthreads();
    int isf = det[0] > 64  ? 1 : 0;
    int i64 = det[1] > 512 ? 1 : 0;

    // ---- block 0: zero counts + all barrier words, then release ready magic ----
    if(bid==0){
        for(int i=t;i<NODES;i+=256) counts[i]=0;
        for(int i=t;i<576;i+=256) bar[i]=0;
        __syncthreads();
        if(t==0)
            __hip_atomic_store(&bar[0], (int)MAGIC, __ATOMIC_RELEASE, __HIP_MEMORY_SCOPE_AGENT);
    }

    // ---- dense1: x@W1 + alpha1 for 8 nodes per block (overlaps block0 init) ----
    {
        struct S1 { float w1[FIN*HC1]; float av[64]; float dv[64]; float xr[8][FIN]; float hrow[8][HC1]; };
        S1* sp = reinterpret_cast<S1*>(smem);
        int n0 = bid*8;
        for(int i=t;i<FIN*HC1;i+=256) sp->w1[i] = ldf(W1,i,isf);
        if(t<64){ sp->av[t]=ldf(as1w,t,isf); sp->dv[t]=ldf(ad1w,t,isf); }
        if(t<128) sp->xr[t>>4][t&15] = ldf(x, n0*FIN + t, isf);
        __syncthreads();
        #pragma unroll
        for(int rep=0;rep<2;rep++){
            int idx = rep*256 + t;
            int r = idx>>6, c = idx&63;
            float acc = 0.f;
            #pragma unroll
            for(int k=0;k<FIN;k++) acc += sp->xr[r][k]*sp->w1[k*HC1+c];
            g1[(n0+r)*HC1 + c] = acc;
            sp->hrow[r][c] = acc;
        }
        __syncthreads();
        if(t<64){
            int ii=t>>3, h=t&7;
            float sa=0.f, sd=0.f;
            #pragma unroll
            for(int k=0;k<8;k++){ float v=sp->hrow[ii][h*8+k]; sa+=v*sp->av[h*8+k]; sd+=v*sp->dv[h*8+k]; }
            as1[(n0+ii)*8+h]=sa; ad1[(n0+ii)*8+h]=sd;
        }
        __syncthreads();
    }

    // ---- gate: wait for counts zeroed + barrier words initialized ----
    if(bid!=0){
        if(t==0){
            while(__hip_atomic_load(&bar[0], __ATOMIC_RELAXED, __HIP_MEMORY_SCOPE_AGENT) != (int)MAGIC)
                __builtin_amdgcn_s_sleep(4);
            __builtin_amdgcn_fence(__ATOMIC_ACQUIRE, "agent");
        }
        __syncthreads();
    }

    // ---- P1: degree count ----
    for(int e = bid*256 + t; e < E; e += NBLK*256)
        atomicAdd(&counts[edst(ed,e,E,i64)], 1);
    __syncthreads();
    if(t==0){
        garrive(bar,bid);                      // gen -> 1 when all arrive
        gwait(bar, bid==0 ? 1 : 2);            // non-0 blocks wait straight for scan-done
    }
    __syncthreads();

    // ---- P2: exclusive scan (block 0 only) then signal gen->2 ----
    if(bid==0){
        int* ssum = reinterpret_cast<int*>(smem);
        int base = t*32;
        int loc[32]; int s = 0;
        #pragma unroll
        for(int k=0;k<32;k++){ loc[k]=s; s+=counts[base+k]; }
        ssum[t]=s;
        __syncthreads();
        for(int off=1;off<256;off<<=1){
            int v = (t>=off)? ssum[t-off] : 0;
            __syncthreads();
            ssum[t]+=v;
            __syncthreads();
        }
        int b0 = t ? ssum[t-1] : 0;
        #pragma unroll
        for(int k=0;k<32;k++){ int v=b0+loc[k]; offs[base+k]=v; cursor[base+k]=v; }
        if(t==255) offs[NODES]=ssum[255];
        __syncthreads();
        if(t==0)
            __hip_atomic_fetch_add(&bar[16], 1, __ATOMIC_RELEASE, __HIP_MEMORY_SCOPE_AGENT); // gen -> 2
    }

    // ---- P3: CSR fill ----
    for(int e = bid*256 + t; e < E; e += NBLK*256){
        int p = atomicAdd(&cursor[edst(ed,e,E,i64)], 1);
        csr[p] = esrc(ed,e,i64);
    }
    __syncthreads();
    if(t==0){ garrive(bar,bid); gwait(bar,3); }
    __syncthreads();

    // ---- P4: agg1 (z1 in LDS) + dense2 + alpha2, 8 nodes per block ----
    {
        struct S2 { float avs[HC2]; float ads[HC2]; float zr[8][HC1]; };
        S2* sp = reinterpret_cast<S2*>(smem);
        int n0 = bid*8;
        for(int i=t;i<HC2;i+=256){ sp->avs[i]=ldf(as2w,i,isf); sp->ads[i]=ldf(ad2w,i,isf); }
        for(int u=0;u<2;u++){
            int n = n0 + wv*2 + u;
            int off = offs[n], deg = offs[n+1]-off, tot = deg+1;
            int h = lane&7;
            float adl = ad1[n*8+h];
            float m=-1e30f, d=0.f;
            for(int j=lane>>3;j<tot;j+=8){
                int s_ = (j<deg)?csr[off+j]:n;
                float e = lrelu(as1[s_*8+h]+adl);
                if(e>m){ d=d*__expf(m-e)+1.f; m=e; } else d+=__expf(e-m);
            }
            #pragma unroll
            for(int st=8;st<64;st<<=1){
                float m2=__shfl_xor(m,st), d2=__shfl_xor(d,st);
                float mm=fmaxf(m,m2);
                d=d*__expf(m-mm)+d2*__expf(m2-mm);
                m=mm;
            }
            float dfin = d + 1e-16f;
            int hc = lane>>3;
            float Mc=__shfl(m,hc), Dc=__shfl(dfin,hc), Ac=__shfl(adl,hc);
            float acc=0.f;
            for(int j=0;j<tot;j++){
                int s_=(j<deg)?csr[off+j]:n;
                float e=lrelu(as1[s_*8+hc]+Ac);
                acc += __expf(e-Mc)*g1[s_*HC1+lane];
            }
            sp->zr[wv*2+u][lane] = fmaxf(acc/Dc + ldf(b1,lane,isf), 0.f);
        }
        __syncthreads();
        int c0 = t*4;
        float acc[8][4];
        #pragma unroll
        for(int i=0;i<8;i++){ acc[i][0]=0;acc[i][1]=0;acc[i][2]=0;acc[i][3]=0; }
        for(int k=0;k<HC1;k++){
            float w0,w1,w2,w3;
            if(isf){
                float4 w = *(const float4*)((const float*)W2 + (size_t)k*HC2 + c0);
                w0=w.x; w1=w.y; w2=w.z; w3=w.w;
            } else {
                ushort4 w = *(const ushort4*)((const u16*)W2 + (size_t)k*HC2 + c0);
                w0=b2f(w.x); w1=b2f(w.y); w2=b2f(w.z); w3=b2f(w.w);
            }
            #pragma unroll
            for(int i=0;i<8;i++){
                float zv = sp->zr[i][k];
                acc[i][0]+=zv*w0; acc[i][1]+=zv*w1; acc[i][2]+=zv*w2; acc[i][3]+=zv*w3;
            }
        }
        float a0=sp->avs[c0], a1=sp->avs[c0+1], a2=sp->avs[c0+2], a3=sp->avs[c0+3];
        float d0=sp->ads[c0], d1=sp->ads[c0+1], d2=sp->ads[c0+2], d3=sp->ads[c0+3];
        int hh = t>>5;
        #pragma unroll
        for(int i=0;i<8;i++){
            ushort4 o;
            o.x=f2b(acc[i][0]); o.y=f2b(acc[i][1]); o.z=f2b(acc[i][2]); o.w=f2b(acc[i][3]);
            *(ushort4*)&g2[(size_t)(n0+i)*HC2 + c0] = o;
            float pa = acc[i][0]*a0 + acc[i][1]*a1 + acc[i][2]*a2 + acc[i][3]*a3;
            float pd = acc[i][0]*d0 + acc[i][1]*d1 + acc[i][2]*d2 + acc[i][3]*d3;
            #pragma unroll
            for(int mm=1;mm<32;mm<<=1){ pa += __shfl_xor(pa,mm); pd += __shfl_xor(pd,mm); }
            if((t&31)==0){ as2[(n0+i)*8+hh]=pa; ad2[(n0+i)*8+hh]=pd; }
        }
    }
    __syncthreads();
    if(t==0){ garrive(bar,bid); gwait(bar,4); }
    __syncthreads();

    // ---- P5: agg2: 2 nodes per wave ----
    {
        int n0 = bid*8;
        for(int u=0;u<2;u++){
            int n = n0 + wv*2 + u;
            int off = offs[n], deg = offs[n+1]-off, tot = deg+1;
            int h = lane&7;
            float adl = ad2[n*8+h];
            float m=-1e30f, d=0.f;
            for(int j=lane>>3;j<tot;j+=8){
                int s_ = (j<deg)?csr[off+j]:n;
                float e = lrelu(as2[s_*8+h]+adl);
                if(e>m){ d=d*__expf(m-e)+1.f; m=e; } else d+=__expf(e-m);
            }
            #pragma unroll
            for(int st=8;st<64;st<<=1){
                float m2=__shfl_xor(m,st), d2=__shfl_xor(d,st);
                float mm=fmaxf(m,m2);
                d=d*__expf(m-mm)+d2*__expf(m2-mm);
                m=mm;
            }
            float dfin = d + 1e-16f;
            float Mq[4], Dq[4], Aq[4];
            int hq[4];
            #pragma unroll
            for(int q=0;q<4;q++){
                hq[q] = q*2 + (lane>>5);
                Mq[q] = __shfl(m,    hq[q]);
                Dq[q] = __shfl(dfin, hq[q]);
                Aq[q] = __shfl(adl,  hq[q]);
            }
            float acc[4][4];
            #pragma unroll
            for(int q=0;q<4;q++){ acc[q][0]=0;acc[q][1]=0;acc[q][2]=0;acc[q][3]=0; }
            for(int j=0;j<tot;j++){
                int s_=(j<deg)?csr[off+j]:n;
                const u16* gp = g2 + (size_t)s_*HC2;
                #pragma unroll
                for(int q=0;q<4;q++){
                    float e = lrelu(as2[s_*8+hq[q]] + Aq[q]);
                    float w = __expf(e - Mq[q]);
                    ushort4 v = *(const ushort4*)&gp[q*256 + lane*4];
                    acc[q][0] += w*b2f(v.x); acc[q][1] += w*b2f(v.y);
                    acc[q][2] += w*b2f(v.z); acc[q][3] += w*b2f(v.w);
                }
            }
            #pragma unroll
            for(int q=0;q<4;q++){
                int c0 = q*256 + lane*4;
                ushort4 o;
                o.x = f2b(fmaxf(acc[q][0]/Dq[q] + ldf(b2,c0+0,isf), 0.f));
                o.y = f2b(fmaxf(acc[q][1]/Dq[q] + ldf(b2,c0+1,isf), 0.f));
                o.z = f2b(fmaxf(acc[q][2]/Dq[q] + ldf(b2,c0+2,isf), 0.f));
                o.w = f2b(fmaxf(acc[q][3]/Dq[q] + ldf(b2,c0+3,isf), 0.f));
                *(ushort4*)&hbf[(size_t)n*HC2 + c0] = o;
            }
        }
    }
    __syncthreads();
    if(t==0){ garrive(bar,bid); gwait(bar,5); }
    __syncthreads();

    // ---- P6: head GEMVs (all 4096 waves), block-level reduce in LDS, one row per block ----
    {
        float* ldsf = reinterpret_cast<float*>(smem);
        int wid = bid*4 + wv;
        gemv_part<64,4096>(v1w,  hbf, ldsf, wv*640,       wid, lane, isf);
        gemv_part<16,4096>(advw, hbf, ldsf, wv*640 + 512, wid, lane, isf);
        __syncthreads();
        for(int i=t;i<640;i+=256){
            float s = ldsf[i] + ldsf[640+i] + ldsf[1280+i] + ldsf[1920+i];
            s1b[(size_t)bid*640 + i] = s;
        }
    }
    __syncthreads();
    if(t==0){
        garrive(bar,bid);
        if(bid<10) gwait(bar,6);
    }
    __syncthreads();
    if(bid>=10) return;

    // ---- P7: reduce s1b[1024][640] -> v1a[512], adva[128] (blocks 0..9, 40 waves) ----
    {
        int w = bid*4 + wv;              // 0..39
        int c0 = w*16;
        int bl = lane>>2, ci=(lane&3)*4;
        float4 a = {0,0,0,0};
        for(int b0=0;b0<NBLK;b0+=16){
            float4 v = *(const float4*)(s1b + (size_t)(b0+bl)*640 + c0 + ci);
            a.x+=v.x; a.y+=v.y; a.z+=v.z; a.w+=v.w;
        }
        #pragma unroll
        for(int m=4;m<64;m<<=1){
            a.x+=__shfl_xor(a.x,m); a.y+=__shfl_xor(a.y,m);
            a.z+=__shfl_xor(a.z,m); a.w+=__shfl_xor(a.w,m);
        }
        if(lane<4){
            int col = c0 + lane*4;
            if(col<512) *(float4*)&v1a[col] = a;
            else        *(float4*)&adva[col-512] = a;
        }
    }
    __syncthreads();
    if(t==0){
        __builtin_amdgcn_fence(__ATOMIC_RELEASE, "agent");
        __hip_atomic_fetch_add(&bar[48], 1, __ATOMIC_RELAXED, __HIP_MEMORY_SCOPE_AGENT);
        if(bid==0){
            while(__hip_atomic_load(&bar[48], __ATOMIC_RELAXED, __HIP_MEMORY_SCOPE_AGENT) < 10)
                __builtin_amdgcn_s_sleep(4);
            __builtin_amdgcn_fence(__ATOMIC_ACQUIRE, "agent");
        }
    }
    __syncthreads();
    if(bid!=0) return;

    // ---- P8: value MLP + dueling combine (block 0) ----
    {
        struct S3 { float v1[8][64]; float v2[8][64]; float adv[128]; float v3[8]; };
        S3* sp = reinterpret_cast<S3*>(smem);
        #pragma unroll
        for(int rep=0;rep<2;rep++){
            int idx=rep*256+t; int b=idx>>6, j=idx&63;
            sp->v1[b][j] = fmaxf(v1a[idx] + ldf(v1b,j,isf), 0.f);
        }
        if(t<128) sp->adv[t] = fmaxf(adva[t] + ldf(advb,t&15,isf), 0.f);
        __syncthreads();
        #pragma unroll
        for(int rep=0;rep<2;rep++){
            int idx=rep*256+t; int b=idx>>6, j=idx&63;
            float a=0.f;
            for(int k=0;k<64;k++) a += sp->v1[b][k]*ldf(v2w,k*64+j,isf);
            sp->v2[b][j] = fmaxf(a + ldf(b2v,j,isf), 0.f);
        }
        __syncthreads();
        if(t<8){
            float a=0.f;
            for(int k=0;k<64;k++) a += sp->v2[t][k]*ldf(v3w,k,isf);
            sp->v3[t] = a + ldf(b3v,0,isf);
        }
        __syncthreads();
        if(t<128){
            int b=t>>4, r=(t>>2)&3;
            int base = b*16 + r*4;
            float mm = 0.25f*(sp->adv[base]+sp->adv[base+1]+sp->adv[base+2]+sp->adv[base+3]);
            float val = sp->v3[b] + sp->adv[t] - mm;
            if(isf) ((float*)out)[t] = val;
            else    ((u16*)out)[t]   = f2b(val);
        }
        if(t==0) __hip_atomic_store(&bar[0], 0, __ATOMIC_RELAXED, __HIP_MEMORY_SCOPE_AGENT);
    }
}

// ---------- host ----------
extern "C" void kernel_launch(void* const* d_in, const int* in_sizes, int n_in,
                              void* d_out, int out_size, void* d_ws, size_t ws_size,
                              hipStream_t stream){
    const void* x    = d_in[0];
    const int*  edge = (const int*)d_in[1];
    const int E = in_sizes[1]/2;
    const void* W1   = d_in[2];
    const void* as1w = d_in[3];
    const void* ad1w = d_in[4];
    const void* b1   = d_in[5];
    const void* W2   = d_in[6];
    const void* as2w = d_in[7];
    const void* ad2w = d_in[8];
    const void* b2   = d_in[9];
    const void* advw = d_in[10];
    const void* advb = d_in[11];
    const void* v1w  = d_in[12];
    const void* v1b  = d_in[13];
    const void* v2w  = d_in[14];
    const void* v2b  = d_in[15];
    const void* v3w  = d_in[16];
    const void* v3b  = d_in[17];

    char* wsp = (char*)d_ws;
    size_t o = 0;
    auto alloc = [&](size_t bytes)->char*{
        char* p = wsp + o;
        o = (o + bytes + 255) & ~(size_t)255;
        return p;
    };
    int*   counts = (int*)  alloc(NODES*4);
    int*   offs   = (int*)  alloc((NODES+8)*4);
    int*   cursor = (int*)  alloc(NODES*4);
    int*   csr    = (int*)  alloc((size_t)E*4);
    float* g1     = (float*)alloc((size_t)NODES*HC1*4);
    float* as1    = (float*)alloc((size_t)NODES*8*4);
    float* ad1    = (float*)alloc((size_t)NODES*8*4);
    u16*   g2     = (u16*)  alloc((size_t)NODES*HC2*2);
    float* as2    = (float*)alloc((size_t)NODES*8*4);
    float* ad2    = (float*)alloc((size_t)NODES*8*4);
    u16*   hbf    = (u16*)  alloc((size_t)NODES*HC2*2);
    float* s1b    = (float*)alloc((size_t)NBLK*640*4);   // 2.62 MB block partials
    float* v1a    = (float*)alloc(512*4);
    float* adva   = (float*)alloc(128*4);
    int*   bar    = (int*)  alloc(4096);

    k_mega<<<NBLK, 256, 0, stream>>>(
        x, edge, E,
        W1, as1w, ad1w, b1,
        W2, as2w, ad2w, b2,
        advw, advb,
        v1w, v1b, v2w, v2b, v3w, v3b,
        counts, offs, cursor, csr,
        g1, as1, ad1,
        g2, as2, ad2, hbf,
        s1b, v1a, adva,
        bar, d_out);
}